// Round 7
// baseline (225.696 us; speedup 1.0000x reference)
//
#include <hip/hip_runtime.h>

#define DIM   1024
#define HEADS 16
#define HDIM  64
#define BATCH 2
#define SEQ   2048
#define TOK   (BATCH*SEQ)   // 4096
#define MEG   1048576

typedef __bf16 bf16x8 __attribute__((ext_vector_type(8)));
typedef float  f32x4  __attribute__((ext_vector_type(4)));

__device__ __forceinline__ float b2f(ushort u) {
    union { unsigned int u32; float f; } x; x.u32 = ((unsigned int)u) << 16; return x.f;
}
__device__ __forceinline__ ushort f2b(float f) {
    union { float f; unsigned int u32; } x; x.f = f;
    unsigned int r = x.u32 + 0x7FFFu + ((x.u32 >> 16) & 1u);
    return (ushort)(r >> 16);
}
__device__ __forceinline__ ushort f2b_t(float f) {   // truncating (for P>=0)
    union { float f; unsigned int u32; } x; x.f = f;
    return (ushort)(x.u32 >> 16);
}
// async global->LDS, 16B per lane; lds dest = wave-uniform base + lane*16
__device__ __forceinline__ void gload_lds16(const ushort* g, void* l) {
    __builtin_amdgcn_global_load_lds((const __attribute__((address_space(1))) void*)g,
                                     (__attribute__((address_space(3))) void*)l, 16, 0, 0);
}

// ------- tiled transpose + fp32->bf16 cast: src f32[R][Cc] -> dst bf16[Cc][R]
__global__ void transpose_f2b_k(const float* __restrict__ src, ushort* __restrict__ dst,
                                int R, int Cc) {
    __shared__ ushort tile[32][33];
    int c0 = blockIdx.x * 32, r0 = blockIdx.y * 32;
    int tx = threadIdx.x, ty = threadIdx.y;   // 32 x 8
#pragma unroll
    for (int i = 0; i < 4; i++)
        tile[ty + 8 * i][tx] = f2b(src[(long)(r0 + ty + 8 * i) * Cc + c0 + tx]);
    __syncthreads();
#pragma unroll
    for (int i = 0; i < 4; i++)
        dst[(long)(c0 + ty + 8 * i) * R + r0 + tx] = tile[tx][ty + 8 * i];
}

// ------- tiled bf16 transpose (for per-head V), batched ----------------------
__global__ void transpose_bf16_k(const ushort* __restrict__ src, ushort* __restrict__ dst,
                                 int R, int Cc, long sstride, long dstride) {
    __shared__ ushort tile[32][33];
    long b = blockIdx.z;
    const ushort* s = src + b * sstride;
    ushort* d = dst + b * dstride;
    int c0 = blockIdx.x * 32, r0 = blockIdx.y * 32;
    int tx = threadIdx.x, ty = threadIdx.y;   // 32 x 8
#pragma unroll
    for (int i = 0; i < 4; i++)
        tile[ty + 8 * i][tx] = s[(long)(r0 + ty + 8 * i) * Cc + c0 + tx];
    __syncthreads();
#pragma unroll
    for (int i = 0; i < 4; i++)
        d[(long)(c0 + ty + 8 * i) * R + r0 + tx] = tile[tx][ty + 8 * i];
}

// ------- LayerNorm: one block per token, fp32 in -> bf16 out -----------------
__global__ __launch_bounds__(256)
void ln_k(const float* __restrict__ x, const float* __restrict__ gamma,
          const float* __restrict__ beta, ushort* __restrict__ h) {
    __shared__ float red[8];
    int row = blockIdx.x, tid = threadIdx.x;
    const float* xr = x + (long)row * DIM;
    float4 xv = *(const float4*)(xr + tid * 4);
    float s1 = xv.x + xv.y + xv.z + xv.w;
    float s2 = xv.x * xv.x + xv.y * xv.y + xv.z * xv.z + xv.w * xv.w;
#pragma unroll
    for (int off = 32; off; off >>= 1) {
        s1 += __shfl_down(s1, off);
        s2 += __shfl_down(s2, off);
    }
    int wid = tid >> 6, lane = tid & 63;
    if (lane == 0) { red[wid * 2] = s1; red[wid * 2 + 1] = s2; }
    __syncthreads();
    s1 = red[0] + red[2] + red[4] + red[6];
    s2 = red[1] + red[3] + red[5] + red[7];
    float mu  = s1 * (1.0f / DIM);
    float var = s2 * (1.0f / DIM) - mu * mu;
    float rs  = rsqrtf(var + 1e-5f);
    float4 gv = *(const float4*)(gamma + tid * 4);
    float4 bv = *(const float4*)(beta + tid * 4);
    ushort4 ov;
    ov.x = f2b((xv.x - mu) * rs * gv.x + bv.x);
    ov.y = f2b((xv.y - mu) * rs * gv.y + bv.y);
    ov.z = f2b((xv.z - mu) * rs * gv.z + bv.z);
    ov.w = f2b((xv.w - mu) * rs * gv.w + bv.w);
    *(ushort4*)(h + (long)row * DIM + tid * 4) = ov;
}

// ------- 128x128 bf16 MFMA GEMM, BK=32, global_load_lds staging (m97 style) --
template <int EPI>
__global__ __launch_bounds__(256, 2)
void gemm128_k(const ushort* __restrict__ A, const ushort* __restrict__ Bt,
               int M, int N, int K,
               ushort* __restrict__ qp, ushort* __restrict__ kp, ushort* __restrict__ vp,
               const float* __restrict__ bias, const float* __restrict__ xres,
               float* __restrict__ outp) {
    __shared__ ushort As[128][32];
    __shared__ ushort Bs[128][32];
    int tid  = threadIdx.x;
    int wid  = tid >> 6, lane = tid & 63;
    int quad = lane >> 4, l16 = lane & 15;
    int wm = wid >> 1, wn = wid & 1;
    int rowbase = blockIdx.y * 128;
    int colbase = blockIdx.x * 128;
    int arow = lane >> 2;            // 0..15 within a 16-row chunk
    int acol = (lane & 3) * 8;       // 0,8,16,24

    f32x4 acc[4][4];
#pragma unroll
    for (int i = 0; i < 4; i++)
#pragma unroll
        for (int j = 0; j < 4; j++) acc[i][j] = (f32x4){0.f, 0.f, 0.f, 0.f};

    for (int k0 = 0; k0 < K; k0 += 32) {
#pragma unroll
        for (int p = 0; p < 2; p++) {
            int c = wid * 2 + p;
            int r = c * 16 + arow;
            const ushort* ga;
            if (EPI == 1) {
                int mm = rowbase + r, cc = k0 + acol;
                int bq = mm >> 11, nn = mm & 2047;
                int head = cc >> 6, d = cc & 63;
                ga = A + ((((long)bq * HEADS + head) * SEQ + nn) << 6) + d;
            } else {
                ga = A + (long)(rowbase + r) * K + k0 + acol;
            }
            gload_lds16(ga, &As[c * 16][0]);
            gload_lds16(Bt + (long)(colbase + r) * K + k0 + acol, &Bs[c * 16][0]);
        }
        __syncthreads();
        bf16x8 fa[4], fb[4];
#pragma unroll
        for (int t = 0; t < 4; t++)
            fa[t] = *(const bf16x8*)(&As[wm * 64 + t * 16 + l16][quad * 8]);
#pragma unroll
        for (int t = 0; t < 4; t++)
            fb[t] = *(const bf16x8*)(&Bs[wn * 64 + t * 16 + l16][quad * 8]);
#pragma unroll
        for (int i = 0; i < 4; i++)
#pragma unroll
            for (int j = 0; j < 4; j++)
                acc[i][j] = __builtin_amdgcn_mfma_f32_16x16x32_bf16(fa[i], fb[j], acc[i][j], 0, 0, 0);
        __syncthreads();
    }

#pragma unroll
    for (int i = 0; i < 4; i++)
#pragma unroll
        for (int j = 0; j < 4; j++) {
            int m0  = rowbase + wm * 64 + i * 16 + quad * 4;
            int col = colbase + wn * 64 + j * 16 + l16;
#pragma unroll
            for (int r = 0; r < 4; r++) {
                float v = acc[i][j][r];
                int mm = m0 + r;
                if (EPI == 0) {
                    int part = col >> 10, rem = col & 1023;
                    int head = rem >> 6, d = rem & 63;
                    int b = mm >> 11, nn = mm & 2047;
                    ushort* dst = (part == 0) ? qp : (part == 1) ? kp : vp;
                    float sv = (part == 0) ? v * 0.125f : v;   // fold 1/sqrt(64) into q
                    dst[((((long)b * HEADS + head) * SEQ + nn) << 6) + d] = f2b(sv);
                } else {
                    outp[(long)mm * N + col] = v + bias[col] + xres[(long)mm * N + col];
                }
            }
        }
}

// ------- flash attention, fixed-max softmax, LDS-staged K/V ------------------
// Block = 128 q-rows of one (b,h); each wave owns TWO 16-row q-subtiles so the
// shared K/V fragment reads are amortized 2x. K tile in two 32-wide panels
// inside one array with +32-ushort panel pad (panel stride 2624 B = 16-bank
// phase shift -> staging-write 8-lane groups cover all 32 banks).
// Output written IN-PLACE into the q buffer ([B,H,N,D]).
__global__ __launch_bounds__(256, 1)
void attn_k(ushort* qio, const ushort* __restrict__ k,
            const ushort* __restrict__ vt) {
    __shared__ ushort Kp[2][2][1312];      // [buf][panel][32*40 + 32 pad]
    __shared__ ushort Vs[2][64][40];       // [buf][d][key]
    __shared__ ushort plds[4][2][16][40];  // [wave][subtile][q][key]
    int bh = blockIdx.y;
    int tid = threadIdx.x, wid = tid >> 6, lane = tid & 63;
    int quad = lane >> 4, l16 = lane & 15;
    ushort* qh = qio + (long)bh * SEQ * HDIM;
    const ushort* kh = k  + (long)bh * SEQ * HDIM;
    const ushort* vh = vt + (long)bh * HDIM * SEQ;

    // staging indices: K: 32 rows x 64 cols (8 thr/row); V^T: 64 rows x 32 cols
    int krow = tid >> 3, kc8 = (tid & 7) * 8;
    int kpan = kc8 >> 5, kcp = kc8 & 31;
    int koff = krow * 40 + kcp;
    int vrow = tid >> 2, vcol = (tid & 3) * 8;

    int qrow0 = blockIdx.x * 128 + wid * 32;
    bf16x8 qf[2][2];
#pragma unroll
    for (int s = 0; s < 2; s++) {
        qf[s][0] = *(const bf16x8*)(qh + (long)(qrow0 + s * 16 + l16) * HDIM + quad * 8);
        qf[s][1] = *(const bf16x8*)(qh + (long)(qrow0 + s * 16 + l16) * HDIM + 32 + quad * 8);
    }

    f32x4 o[2][4];
    f32x4 lac[2][2];
#pragma unroll
    for (int s = 0; s < 2; s++) {
#pragma unroll
        for (int dc = 0; dc < 4; dc++) o[s][dc] = (f32x4){0.f, 0.f, 0.f, 0.f};
        lac[s][0] = (f32x4){0.f, 0.f, 0.f, 0.f};
        lac[s][1] = (f32x4){0.f, 0.f, 0.f, 0.f};
    }

    // prologue: stage tile 0 into buffer 0
    uint4 kreg = *(const uint4*)(kh + (long)krow * HDIM + kc8);
    uint4 vreg = *(const uint4*)(vh + (long)vrow * SEQ + vcol);
    *(uint4*)(&Kp[0][kpan][koff]) = kreg;
    *(uint4*)(&Vs[0][vrow][vcol]) = vreg;

    const int NIT = SEQ / 32;   // 64
    for (int it = 0; it < NIT; ++it) {
        int buf = it & 1;
        if (it + 1 < NIT) {
            int kt = (it + 1) * 32;
            kreg = *(const uint4*)(kh + (long)(kt + krow) * HDIM + kc8);
            vreg = *(const uint4*)(vh + (long)vrow * SEQ + kt + vcol);
        }
        __syncthreads();   // buf tile visible; prior reads of buf^1 done

        // K frags: kb[t][p] = K[key=t*16+l16][d=p*32+quad*8 ..+7]
        bf16x8 kb[2][2];
#pragma unroll
        for (int t = 0; t < 2; t++)
#pragma unroll
            for (int p = 0; p < 2; p++)
                kb[t][p] = *(const bf16x8*)(&Kp[buf][p][(t * 16 + l16) * 40 + quad * 8]);

        // QK^T for both q-subtiles
        f32x4 sc[2][2];
#pragma unroll
        for (int s = 0; s < 2; s++)
#pragma unroll
            for (int t = 0; t < 2; t++) {
                f32x4 z = (f32x4){0.f, 0.f, 0.f, 0.f};
                z = __builtin_amdgcn_mfma_f32_16x16x32_bf16(qf[s][0], kb[t][0], z, 0, 0, 0);
                z = __builtin_amdgcn_mfma_f32_16x16x32_bf16(qf[s][1], kb[t][1], z, 0, 0, 0);
                sc[s][t] = z;
            }

        // exp + l-accum + P write (C-layout -> per-wave LDS)
#pragma unroll
        for (int s = 0; s < 2; s++)
#pragma unroll
            for (int r = 0; r < 4; r++) {
                float p0 = __expf(sc[s][0][r]);
                float p1 = __expf(sc[s][1][r]);
                lac[s][0][r] += p0;
                lac[s][1][r] += p1;
                plds[wid][s][quad * 4 + r][l16]      = f2b_t(p0);
                plds[wid][s][quad * 4 + r][16 + l16] = f2b_t(p1);
            }
        asm volatile("s_waitcnt lgkmcnt(0)" ::: "memory");

        bf16x8 pf[2];
#pragma unroll
        for (int s = 0; s < 2; s++)
            pf[s] = *(const bf16x8*)(&plds[wid][s][l16][quad * 8]);
#pragma unroll
        for (int dc = 0; dc < 4; dc++) {
            bf16x8 vfb = *(const bf16x8*)(&Vs[buf][dc * 16 + l16][quad * 8]);
#pragma unroll
            for (int s = 0; s < 2; s++)
                o[s][dc] = __builtin_amdgcn_mfma_f32_16x16x32_bf16(pf[s], vfb, o[s][dc], 0, 0, 0);
        }

        if (it + 1 < NIT) {
            *(uint4*)(&Kp[buf ^ 1][kpan][koff]) = kreg;
            *(uint4*)(&Vs[buf ^ 1][vrow][vcol]) = vreg;
        }
    }

    // row-sum reduction + in-place writeback, per subtile
#pragma unroll
    for (int s = 0; s < 2; s++) {
        float linv[4];
#pragma unroll
        for (int r = 0; r < 4; r++) {
            float t = lac[s][0][r] + lac[s][1][r];
            t += __shfl_xor(t, 1);
            t += __shfl_xor(t, 2);
            t += __shfl_xor(t, 4);
            t += __shfl_xor(t, 8);
            linv[r] = 1.0f / t;
        }
        int rowo = qrow0 + s * 16 + quad * 4;
#pragma unroll
        for (int dc = 0; dc < 4; dc++)
#pragma unroll
            for (int r = 0; r < 4; r++)
                qh[(long)(rowo + r) * HDIM + dc * 16 + l16] = f2b(o[s][dc][r] * linv[r]);
    }
}

// ------- launch --------------------------------------------------------------
extern "C" void kernel_launch(void* const* d_in, const int* in_sizes, int n_in,
                              void* d_out, int out_size, void* d_ws, size_t ws_size,
                              hipStream_t stream) {
    const float* x      = (const float*)d_in[0];
    const float* w_qkv  = (const float*)d_in[1];
    const float* w_proj = (const float*)d_in[2];
    const float* b_proj = (const float*)d_in[3];
    const float* gamma  = (const float*)d_in[4];
    const float* beta   = (const float*)d_in[5];
    float* out = (float*)d_out;

    // workspace: 19M bf16 elements = 38 MB (slots reused across phases)
    ushort* ws   = (ushort*)d_ws;
    ushort* h_vt = ws;                      // 4M: h (phase 2-3), then V^T (phase 4-5)
    ushort* wqt  = ws + (size_t)4 * MEG;    // 3M: w_qkv^T (bf16)
    ushort* qb   = ws + (size_t)7 * MEG;    // 4M: q (pre-scaled), then attn out (q-layout)
    ushort* kb   = ws + (size_t)11 * MEG;   // 4M: k, then w_proj^T (phase 6-7)
    ushort* vb   = ws + (size_t)15 * MEG;   // 4M: v

    // 1) transpose+cast w_qkv f32[K][3N] -> bf16 [3N][K]
    transpose_f2b_k<<<dim3(3 * DIM / 32, DIM / 32), dim3(32, 8), 0, stream>>>(
        w_qkv, wqt, DIM, 3 * DIM);
    // 2) layernorm f32 -> bf16 h
    ln_k<<<dim3(TOK), dim3(256), 0, stream>>>(x, gamma, beta, h_vt);
    // 3) qkv gemm + scatter to q/k/v (bf16; q pre-scaled by 0.125)
    gemm128_k<0><<<dim3(3 * DIM / 128, TOK / 128), dim3(256), 0, stream>>>(
        h_vt, wqt, TOK, 3 * DIM, DIM, qb, kb, vb, nullptr, nullptr, nullptr);
    // 4) per-head V transpose -> [D][N] (into dead h slot)
    transpose_bf16_k<<<dim3(HDIM / 32, SEQ / 32, BATCH * HEADS), dim3(32, 8), 0, stream>>>(
        vb, h_vt, SEQ, HDIM, (long)SEQ * HDIM, (long)SEQ * HDIM);
    // 5) flash attention; output overwrites q buffer in q-layout
    attn_k<<<dim3(SEQ / 128, BATCH * HEADS), dim3(256), 0, stream>>>(qb, kb, h_vt);
    // 6) transpose+cast w_proj into dead k slot
    transpose_f2b_k<<<dim3(DIM / 32, DIM / 32), dim3(32, 8), 0, stream>>>(
        w_proj, kb, DIM, DIM);
    // 7) proj gemm (+fp32 bias +fp32 residual) -> fp32 out
    gemm128_k<1><<<dim3(DIM / 128, TOK / 128), dim3(256), 0, stream>>>(
        qb, kb, TOK, DIM, DIM, nullptr, nullptr, nullptr, b_proj, x, out);
}

// Round 8
// 204.701 us; speedup vs baseline: 1.1026x; 1.1026x over previous
//
#include <hip/hip_runtime.h>

#define DIM   1024
#define HEADS 16
#define HDIM  64
#define BATCH 2
#define SEQ   2048
#define TOK   (BATCH*SEQ)   // 4096
#define MEG   1048576

typedef __bf16 bf16x8 __attribute__((ext_vector_type(8)));
typedef float  f32x4  __attribute__((ext_vector_type(4)));

__device__ __forceinline__ float b2f(ushort u) {
    union { unsigned int u32; float f; } x; x.u32 = ((unsigned int)u) << 16; return x.f;
}
__device__ __forceinline__ ushort f2b(float f) {
    union { float f; unsigned int u32; } x; x.f = f;
    unsigned int r = x.u32 + 0x7FFFu + ((x.u32 >> 16) & 1u);
    return (ushort)(r >> 16);
}
__device__ __forceinline__ unsigned int pack2bf(float a, float b) {  // trunc, b in hi
    union { float f; unsigned int u; } xa, xb; xa.f = a; xb.f = b;
    return (xb.u & 0xFFFF0000u) | (xa.u >> 16);
}
// async global->LDS, 16B per lane; lds dest = wave-uniform base + lane*16
__device__ __forceinline__ void gload_lds16(const ushort* g, void* l) {
    __builtin_amdgcn_global_load_lds((const __attribute__((address_space(1))) void*)g,
                                     (__attribute__((address_space(3))) void*)l, 16, 0, 0);
}

// ------- tiled transpose + fp32->bf16 cast: src f32[R][Cc] -> dst bf16[Cc][R]
__global__ void transpose_f2b_k(const float* __restrict__ src, ushort* __restrict__ dst,
                                int R, int Cc) {
    __shared__ ushort tile[32][33];
    int c0 = blockIdx.x * 32, r0 = blockIdx.y * 32;
    int tx = threadIdx.x, ty = threadIdx.y;   // 32 x 8
#pragma unroll
    for (int i = 0; i < 4; i++)
        tile[ty + 8 * i][tx] = f2b(src[(long)(r0 + ty + 8 * i) * Cc + c0 + tx]);
    __syncthreads();
#pragma unroll
    for (int i = 0; i < 4; i++)
        dst[(long)(c0 + ty + 8 * i) * R + r0 + tx] = tile[tx][ty + 8 * i];
}

// ------- tiled bf16 transpose (for per-head V), batched ----------------------
__global__ void transpose_bf16_k(const ushort* __restrict__ src, ushort* __restrict__ dst,
                                 int R, int Cc, long sstride, long dstride) {
    __shared__ ushort tile[32][33];
    long b = blockIdx.z;
    const ushort* s = src + b * sstride;
    ushort* d = dst + b * dstride;
    int c0 = blockIdx.x * 32, r0 = blockIdx.y * 32;
    int tx = threadIdx.x, ty = threadIdx.y;   // 32 x 8
#pragma unroll
    for (int i = 0; i < 4; i++)
        tile[ty + 8 * i][tx] = s[(long)(r0 + ty + 8 * i) * Cc + c0 + tx];
    __syncthreads();
#pragma unroll
    for (int i = 0; i < 4; i++)
        d[(long)(c0 + ty + 8 * i) * R + r0 + tx] = tile[tx][ty + 8 * i];
}

// ------- LayerNorm: one block per token, fp32 in -> bf16 out -----------------
__global__ __launch_bounds__(256)
void ln_k(const float* __restrict__ x, const float* __restrict__ gamma,
          const float* __restrict__ beta, ushort* __restrict__ h) {
    __shared__ float red[8];
    int row = blockIdx.x, tid = threadIdx.x;
    const float* xr = x + (long)row * DIM;
    float4 xv = *(const float4*)(xr + tid * 4);
    float s1 = xv.x + xv.y + xv.z + xv.w;
    float s2 = xv.x * xv.x + xv.y * xv.y + xv.z * xv.z + xv.w * xv.w;
#pragma unroll
    for (int off = 32; off; off >>= 1) {
        s1 += __shfl_down(s1, off);
        s2 += __shfl_down(s2, off);
    }
    int wid = tid >> 6, lane = tid & 63;
    if (lane == 0) { red[wid * 2] = s1; red[wid * 2 + 1] = s2; }
    __syncthreads();
    s1 = red[0] + red[2] + red[4] + red[6];
    s2 = red[1] + red[3] + red[5] + red[7];
    float mu  = s1 * (1.0f / DIM);
    float var = s2 * (1.0f / DIM) - mu * mu;
    float rs  = rsqrtf(var + 1e-5f);
    float4 gv = *(const float4*)(gamma + tid * 4);
    float4 bv = *(const float4*)(beta + tid * 4);
    ushort4 ov;
    ov.x = f2b((xv.x - mu) * rs * gv.x + bv.x);
    ov.y = f2b((xv.y - mu) * rs * gv.y + bv.y);
    ov.z = f2b((xv.z - mu) * rs * gv.z + bv.z);
    ov.w = f2b((xv.w - mu) * rs * gv.w + bv.w);
    *(ushort4*)(h + (long)row * DIM + tid * 4) = ov;
}

// ------- 128x128 bf16 MFMA GEMM, BK=64 (two 32-col panels), global_load_lds --
// 32 MFMA between barrier pairs; 16 K-iterations at K=1024.
// EPI 0: scatter C to q/k/v bf16 [B,H,N,D]; q pre-scaled by 1/sqrt(HDIM).
// EPI 1: A in q-layout [B,H,N,D]; C + fp32 bias + fp32 residual -> fp32 out.
template <int EPI>
__global__ __launch_bounds__(256, 2)
void gemm128_k(const ushort* __restrict__ A, const ushort* __restrict__ Bt,
               int M, int N, int K,
               ushort* __restrict__ qp, ushort* __restrict__ kp, ushort* __restrict__ vp,
               const float* __restrict__ bias, const float* __restrict__ xres,
               float* __restrict__ outp) {
    __shared__ ushort As[2][128][32];   // [panel][row][k 0..31 / 32..63]
    __shared__ ushort Bs[2][128][32];
    int tid  = threadIdx.x;
    int wid  = tid >> 6, lane = tid & 63;
    int quad = lane >> 4, l16 = lane & 15;
    int wm = wid >> 1, wn = wid & 1;
    int rowbase = blockIdx.y * 128;
    int colbase = blockIdx.x * 128;
    int arow = lane >> 2;            // 0..15 within a 16-row chunk
    int acol = (lane & 3) * 8;       // 0,8,16,24

    f32x4 acc[4][4];
#pragma unroll
    for (int i = 0; i < 4; i++)
#pragma unroll
        for (int j = 0; j < 4; j++) acc[i][j] = (f32x4){0.f, 0.f, 0.f, 0.f};

    for (int k0 = 0; k0 < K; k0 += 64) {
#pragma unroll
        for (int p = 0; p < 2; p++) {
            int c = wid * 2 + p;
            int r = c * 16 + arow;
#pragma unroll
            for (int pnl = 0; pnl < 2; pnl++) {
                int cc = k0 + pnl * 32 + acol;
                const ushort* ga;
                if (EPI == 1) {
                    int mm = rowbase + r;
                    int bq = mm >> 11, nn = mm & 2047;
                    int head = cc >> 6, d = cc & 63;
                    ga = A + ((((long)bq * HEADS + head) * SEQ + nn) << 6) + d;
                } else {
                    ga = A + (long)(rowbase + r) * K + cc;
                }
                gload_lds16(ga, &As[pnl][c * 16][0]);
                gload_lds16(Bt + (long)(colbase + r) * K + cc, &Bs[pnl][c * 16][0]);
            }
        }
        __syncthreads();
#pragma unroll
        for (int pnl = 0; pnl < 2; pnl++) {
            bf16x8 fa[4], fb[4];
#pragma unroll
            for (int t = 0; t < 4; t++)
                fa[t] = *(const bf16x8*)(&As[pnl][wm * 64 + t * 16 + l16][quad * 8]);
#pragma unroll
            for (int t = 0; t < 4; t++)
                fb[t] = *(const bf16x8*)(&Bs[pnl][wn * 64 + t * 16 + l16][quad * 8]);
#pragma unroll
            for (int i = 0; i < 4; i++)
#pragma unroll
                for (int j = 0; j < 4; j++)
                    acc[i][j] = __builtin_amdgcn_mfma_f32_16x16x32_bf16(fa[i], fb[j], acc[i][j], 0, 0, 0);
        }
        __syncthreads();
    }

#pragma unroll
    for (int i = 0; i < 4; i++)
#pragma unroll
        for (int j = 0; j < 4; j++) {
            int m0  = rowbase + wm * 64 + i * 16 + quad * 4;
            int col = colbase + wn * 64 + j * 16 + l16;
#pragma unroll
            for (int r = 0; r < 4; r++) {
                float v = acc[i][j][r];
                int mm = m0 + r;
                if (EPI == 0) {
                    int part = col >> 10, rem = col & 1023;
                    int head = rem >> 6, d = rem & 63;
                    int b = mm >> 11, nn = mm & 2047;
                    ushort* dst = (part == 0) ? qp : (part == 1) ? kp : vp;
                    float sv = (part == 0) ? v * 0.125f : v;   // fold 1/sqrt(64) into q
                    dst[((((long)b * HEADS + head) * SEQ + nn) << 6) + d] = f2b(sv);
                } else {
                    outp[(long)mm * N + col] = v + bias[col] + xres[(long)mm * N + col];
                }
            }
        }
}

// ------- flash attention, fixed-max softmax, LDS-staged K/V ------------------
// Block = 128 q-rows of one (b,h); each wave owns TWO 16-row q-subtiles.
// QK^T computed with SWAPPED operands -> C[key][q]: each lane holds 4
// consecutive keys for one q, so the P C->A transform is 2 ds_write_b64
// per subtile (was 16 ds_write_b16 total). l-sum reduction fully hoisted
// out of the loop. Output written IN-PLACE into the q buffer ([B,H,N,D]).
__global__ __launch_bounds__(256, 2)
void attn_k(ushort* qio, const ushort* __restrict__ k,
            const ushort* __restrict__ vt) {
    __shared__ ushort Kp[2][2][1312];      // [buf][panel][32*40 + 32 pad]
    __shared__ ushort Vs[2][64][40];       // [buf][d][key]
    __shared__ ushort plds[4][2][16][40];  // [wave][subtile][q][key]
    int bh = blockIdx.y;
    int tid = threadIdx.x, wid = tid >> 6, lane = tid & 63;
    int quad = lane >> 4, l16 = lane & 15;
    ushort* qh = qio + (long)bh * SEQ * HDIM;
    const ushort* kh = k  + (long)bh * SEQ * HDIM;
    const ushort* vh = vt + (long)bh * HDIM * SEQ;

    // staging indices: K: 32 rows x 64 cols (8 thr/row); V^T: 64 rows x 32 cols
    int krow = tid >> 3, kc8 = (tid & 7) * 8;
    int kpan = kc8 >> 5, kcp = kc8 & 31;
    int koff = krow * 40 + kcp;
    int vrow = tid >> 2, vcol = (tid & 3) * 8;

    int qrow0 = blockIdx.x * 128 + wid * 32;
    bf16x8 qf[2][2];
#pragma unroll
    for (int s = 0; s < 2; s++) {
        qf[s][0] = *(const bf16x8*)(qh + (long)(qrow0 + s * 16 + l16) * HDIM + quad * 8);
        qf[s][1] = *(const bf16x8*)(qh + (long)(qrow0 + s * 16 + l16) * HDIM + 32 + quad * 8);
    }

    f32x4 o[2][4];
    f32x4 lac[2][2];
#pragma unroll
    for (int s = 0; s < 2; s++) {
#pragma unroll
        for (int dc = 0; dc < 4; dc++) o[s][dc] = (f32x4){0.f, 0.f, 0.f, 0.f};
        lac[s][0] = (f32x4){0.f, 0.f, 0.f, 0.f};
        lac[s][1] = (f32x4){0.f, 0.f, 0.f, 0.f};
    }

    // prologue: stage tile 0 into buffer 0
    uint4 kreg = *(const uint4*)(kh + (long)krow * HDIM + kc8);
    uint4 vreg = *(const uint4*)(vh + (long)vrow * SEQ + vcol);
    *(uint4*)(&Kp[0][kpan][koff]) = kreg;
    *(uint4*)(&Vs[0][vrow][vcol]) = vreg;

    const int NIT = SEQ / 32;   // 64
    for (int it = 0; it < NIT; ++it) {
        int buf = it & 1;
        if (it + 1 < NIT) {
            int kt = (it + 1) * 32;
            kreg = *(const uint4*)(kh + (long)(kt + krow) * HDIM + kc8);
            vreg = *(const uint4*)(vh + (long)vrow * SEQ + kt + vcol);
        }
        __syncthreads();   // buf tile visible; prior reads of buf^1 done

        // K frags: kb[t][p] = K[key=t*16+l16][d=p*32+quad*8 ..+7]
        bf16x8 kb[2][2];
#pragma unroll
        for (int t = 0; t < 2; t++)
#pragma unroll
            for (int p = 0; p < 2; p++)
                kb[t][p] = *(const bf16x8*)(&Kp[buf][p][(t * 16 + l16) * 40 + quad * 8]);

        // QK^T SWAPPED: C[key][q] — col=l16=q, row=quad*4+r=key(+t*16)
        f32x4 sc[2][2];
#pragma unroll
        for (int s = 0; s < 2; s++)
#pragma unroll
            for (int t = 0; t < 2; t++) {
                f32x4 z = (f32x4){0.f, 0.f, 0.f, 0.f};
                z = __builtin_amdgcn_mfma_f32_16x16x32_bf16(kb[t][0], qf[s][0], z, 0, 0, 0);
                z = __builtin_amdgcn_mfma_f32_16x16x32_bf16(kb[t][1], qf[s][1], z, 0, 0, 0);
                sc[s][t] = z;
            }

        // exp + l-accum + packed P write: lane owns keys t*16+quad*4..+3 for q=l16
#pragma unroll
        for (int s = 0; s < 2; s++)
#pragma unroll
            for (int t = 0; t < 2; t++) {
                float e0 = __expf(sc[s][t][0]);
                float e1 = __expf(sc[s][t][1]);
                float e2 = __expf(sc[s][t][2]);
                float e3 = __expf(sc[s][t][3]);
                lac[s][t] += (f32x4){e0, e1, e2, e3};
                uint2 pk;
                pk.x = pack2bf(e0, e1);
                pk.y = pack2bf(e2, e3);
                *(uint2*)(&plds[wid][s][l16][t * 16 + quad * 4]) = pk;
            }
        asm volatile("s_waitcnt lgkmcnt(0)" ::: "memory");

        bf16x8 pf[2];
#pragma unroll
        for (int s = 0; s < 2; s++)
            pf[s] = *(const bf16x8*)(&plds[wid][s][l16][quad * 8]);
#pragma unroll
        for (int dc = 0; dc < 4; dc++) {
            bf16x8 vfb = *(const bf16x8*)(&Vs[buf][dc * 16 + l16][quad * 8]);
#pragma unroll
            for (int s = 0; s < 2; s++)
                o[s][dc] = __builtin_amdgcn_mfma_f32_16x16x32_bf16(pf[s], vfb, o[s][dc], 0, 0, 0);
        }

        if (it + 1 < NIT) {
            *(uint4*)(&Kp[buf ^ 1][kpan][koff]) = kreg;
            *(uint4*)(&Vs[buf ^ 1][vrow][vcol]) = vreg;
        }
    }

    // l-reduction: lane (l16=q) holds partials over keys {t*16+quad*4+r};
    // in-lane sum over t,r then across quads (xor 16, 32) -> every lane has l[q=l16]
#pragma unroll
    for (int s = 0; s < 2; s++) {
        f32x4 lv = lac[s][0] + lac[s][1];
        float t = lv[0] + lv[1] + lv[2] + lv[3];
        t += __shfl_xor(t, 16);
        t += __shfl_xor(t, 32);
        float linv_q = 1.0f / t;   // valid for q = l16 in every lane
        // o is C-layout [q][d]: row q = quad*4+r, col d = l16
        float linv[4];
#pragma unroll
        for (int r = 0; r < 4; r++)
            linv[r] = __shfl(linv_q, quad * 4 + r);
        int rowo = qrow0 + s * 16 + quad * 4;
#pragma unroll
        for (int dc = 0; dc < 4; dc++)
#pragma unroll
            for (int r = 0; r < 4; r++)
                qh[(long)(rowo + r) * HDIM + dc * 16 + l16] = f2b(o[s][dc][r] * linv[r]);
    }
}

// ------- launch --------------------------------------------------------------
extern "C" void kernel_launch(void* const* d_in, const int* in_sizes, int n_in,
                              void* d_out, int out_size, void* d_ws, size_t ws_size,
                              hipStream_t stream) {
    const float* x      = (const float*)d_in[0];
    const float* w_qkv  = (const float*)d_in[1];
    const float* w_proj = (const float*)d_in[2];
    const float* b_proj = (const float*)d_in[3];
    const float* gamma  = (const float*)d_in[4];
    const float* beta   = (const float*)d_in[5];
    float* out = (float*)d_out;

    // workspace: 19M bf16 elements = 38 MB (slots reused across phases)
    ushort* ws   = (ushort*)d_ws;
    ushort* h_vt = ws;                      // 4M: h (phase 2-3), then V^T (phase 4-5)
    ushort* wqt  = ws + (size_t)4 * MEG;    // 3M: w_qkv^T (bf16)
    ushort* qb   = ws + (size_t)7 * MEG;    // 4M: q (pre-scaled), then attn out (q-layout)
    ushort* kb   = ws + (size_t)11 * MEG;   // 4M: k, then w_proj^T (phase 6-7)
    ushort* vb   = ws + (size_t)15 * MEG;   // 4M: v

    // 1) transpose+cast w_qkv f32[K][3N] -> bf16 [3N][K]
    transpose_f2b_k<<<dim3(3 * DIM / 32, DIM / 32), dim3(32, 8), 0, stream>>>(
        w_qkv, wqt, DIM, 3 * DIM);
    // 2) layernorm f32 -> bf16 h
    ln_k<<<dim3(TOK), dim3(256), 0, stream>>>(x, gamma, beta, h_vt);
    // 3) qkv gemm + scatter to q/k/v (bf16; q pre-scaled by 0.125)
    gemm128_k<0><<<dim3(3 * DIM / 128, TOK / 128), dim3(256), 0, stream>>>(
        h_vt, wqt, TOK, 3 * DIM, DIM, qb, kb, vb, nullptr, nullptr, nullptr);
    // 4) per-head V transpose -> [D][N] (into dead h slot)
    transpose_bf16_k<<<dim3(HDIM / 32, SEQ / 32, BATCH * HEADS), dim3(32, 8), 0, stream>>>(
        vb, h_vt, SEQ, HDIM, (long)SEQ * HDIM, (long)SEQ * HDIM);
    // 5) flash attention; output overwrites q buffer in q-layout
    attn_k<<<dim3(SEQ / 128, BATCH * HEADS), dim3(256), 0, stream>>>(qb, kb, h_vt);
    // 6) transpose+cast w_proj into dead k slot
    transpose_f2b_k<<<dim3(DIM / 32, DIM / 32), dim3(32, 8), 0, stream>>>(
        w_proj, kb, DIM, DIM);
    // 7) proj gemm (+fp32 bias +fp32 residual) -> fp32 out
    gemm128_k<1><<<dim3(DIM / 128, TOK / 128), dim3(256), 0, stream>>>(
        qb, kb, TOK, DIM, DIM, nullptr, nullptr, nullptr, b_proj, x, out);
}

// Round 9
// 200.987 us; speedup vs baseline: 1.1229x; 1.0185x over previous
//
#include <hip/hip_runtime.h>

#define DIM   1024
#define HEADS 16
#define HDIM  64
#define BATCH 2
#define SEQ   2048
#define TOK   (BATCH*SEQ)   // 4096
#define MEG   1048576

typedef __bf16 bf16x8 __attribute__((ext_vector_type(8)));
typedef float  f32x4  __attribute__((ext_vector_type(4)));

__device__ __forceinline__ float b2f(ushort u) {
    union { unsigned int u32; float f; } x; x.u32 = ((unsigned int)u) << 16; return x.f;
}
__device__ __forceinline__ ushort f2b(float f) {
    union { float f; unsigned int u32; } x; x.f = f;
    unsigned int r = x.u32 + 0x7FFFu + ((x.u32 >> 16) & 1u);
    return (ushort)(r >> 16);
}
__device__ __forceinline__ unsigned int pack2bf(float a, float b) {  // trunc, b in hi
    union { float f; unsigned int u; } xa, xb; xa.f = a; xb.f = b;
    return (xb.u & 0xFFFF0000u) | (xa.u >> 16);
}
// async global->LDS, 16B per lane; lds dest = wave-uniform base + lane*16
__device__ __forceinline__ void gload_lds16(const ushort* g, void* l) {
    __builtin_amdgcn_global_load_lds((const __attribute__((address_space(1))) void*)g,
                                     (__attribute__((address_space(3))) void*)l, 16, 0, 0);
}

// ------- tiled transpose + fp32->bf16 cast: src f32[R][Cc] -> dst bf16[Cc][R]
__global__ void transpose_f2b_k(const float* __restrict__ src, ushort* __restrict__ dst,
                                int R, int Cc) {
    __shared__ ushort tile[32][33];
    int c0 = blockIdx.x * 32, r0 = blockIdx.y * 32;
    int tx = threadIdx.x, ty = threadIdx.y;   // 32 x 8
#pragma unroll
    for (int i = 0; i < 4; i++)
        tile[ty + 8 * i][tx] = f2b(src[(long)(r0 + ty + 8 * i) * Cc + c0 + tx]);
    __syncthreads();
#pragma unroll
    for (int i = 0; i < 4; i++)
        dst[(long)(c0 + ty + 8 * i) * R + r0 + tx] = tile[tx][ty + 8 * i];
}

// ------- tiled bf16 transpose (for per-head V), batched ----------------------
__global__ void transpose_bf16_k(const ushort* __restrict__ src, ushort* __restrict__ dst,
                                 int R, int Cc, long sstride, long dstride) {
    __shared__ ushort tile[32][33];
    long b = blockIdx.z;
    const ushort* s = src + b * sstride;
    ushort* d = dst + b * dstride;
    int c0 = blockIdx.x * 32, r0 = blockIdx.y * 32;
    int tx = threadIdx.x, ty = threadIdx.y;   // 32 x 8
#pragma unroll
    for (int i = 0; i < 4; i++)
        tile[ty + 8 * i][tx] = s[(long)(r0 + ty + 8 * i) * Cc + c0 + tx];
    __syncthreads();
#pragma unroll
    for (int i = 0; i < 4; i++)
        d[(long)(c0 + ty + 8 * i) * R + r0 + tx] = tile[tx][ty + 8 * i];
}

// ------- LayerNorm: one block per token, fp32 in -> bf16 out -----------------
__global__ __launch_bounds__(256)
void ln_k(const float* __restrict__ x, const float* __restrict__ gamma,
          const float* __restrict__ beta, ushort* __restrict__ h) {
    __shared__ float red[8];
    int row = blockIdx.x, tid = threadIdx.x;
    const float* xr = x + (long)row * DIM;
    float4 xv = *(const float4*)(xr + tid * 4);
    float s1 = xv.x + xv.y + xv.z + xv.w;
    float s2 = xv.x * xv.x + xv.y * xv.y + xv.z * xv.z + xv.w * xv.w;
#pragma unroll
    for (int off = 32; off; off >>= 1) {
        s1 += __shfl_down(s1, off);
        s2 += __shfl_down(s2, off);
    }
    int wid = tid >> 6, lane = tid & 63;
    if (lane == 0) { red[wid * 2] = s1; red[wid * 2 + 1] = s2; }
    __syncthreads();
    s1 = red[0] + red[2] + red[4] + red[6];
    s2 = red[1] + red[3] + red[5] + red[7];
    float mu  = s1 * (1.0f / DIM);
    float var = s2 * (1.0f / DIM) - mu * mu;
    float rs  = rsqrtf(var + 1e-5f);
    float4 gv = *(const float4*)(gamma + tid * 4);
    float4 bv = *(const float4*)(beta + tid * 4);
    ushort4 ov;
    ov.x = f2b((xv.x - mu) * rs * gv.x + bv.x);
    ov.y = f2b((xv.y - mu) * rs * gv.y + bv.y);
    ov.z = f2b((xv.z - mu) * rs * gv.z + bv.z);
    ov.w = f2b((xv.w - mu) * rs * gv.w + bv.w);
    *(ushort4*)(h + (long)row * DIM + tid * 4) = ov;
}

// ------- QKV GEMM: 128x128 tile, BK=64 (two 32-col panels), global_load_lds --
// 32 MFMA between barrier pairs; 16 K-iterations at K=1024; 3 blocks/CU.
// Scatter C to q/k/v bf16 [B,H,N,D]; q pre-scaled by 1/sqrt(HDIM).
__global__ __launch_bounds__(256, 3)
void gemm_qkv_k(const ushort* __restrict__ A, const ushort* __restrict__ Bt,
                ushort* __restrict__ qp, ushort* __restrict__ kp, ushort* __restrict__ vp) {
    __shared__ ushort As[2][128][32];   // [panel][row][k 0..31 / 32..63]
    __shared__ ushort Bs[2][128][32];
    int tid  = threadIdx.x;
    int wid  = tid >> 6, lane = tid & 63;
    int quad = lane >> 4, l16 = lane & 15;
    int wm = wid >> 1, wn = wid & 1;
    int rowbase = blockIdx.y * 128;
    int colbase = blockIdx.x * 128;
    int arow = lane >> 2;            // 0..15 within a 16-row chunk
    int acol = (lane & 3) * 8;       // 0,8,16,24

    f32x4 acc[4][4];
#pragma unroll
    for (int i = 0; i < 4; i++)
#pragma unroll
        for (int j = 0; j < 4; j++) acc[i][j] = (f32x4){0.f, 0.f, 0.f, 0.f};

    for (int k0 = 0; k0 < DIM; k0 += 64) {
#pragma unroll
        for (int p = 0; p < 2; p++) {
            int c = wid * 2 + p;
            int r = c * 16 + arow;
#pragma unroll
            for (int pnl = 0; pnl < 2; pnl++) {
                int cc = k0 + pnl * 32 + acol;
                gload_lds16(A  + (long)(rowbase + r) * DIM + cc, &As[pnl][c * 16][0]);
                gload_lds16(Bt + (long)(colbase + r) * DIM + cc, &Bs[pnl][c * 16][0]);
            }
        }
        __syncthreads();
#pragma unroll
        for (int pnl = 0; pnl < 2; pnl++) {
            bf16x8 fa[4], fb[4];
#pragma unroll
            for (int t = 0; t < 4; t++)
                fa[t] = *(const bf16x8*)(&As[pnl][wm * 64 + t * 16 + l16][quad * 8]);
#pragma unroll
            for (int t = 0; t < 4; t++)
                fb[t] = *(const bf16x8*)(&Bs[pnl][wn * 64 + t * 16 + l16][quad * 8]);
#pragma unroll
            for (int i = 0; i < 4; i++)
#pragma unroll
                for (int j = 0; j < 4; j++)
                    acc[i][j] = __builtin_amdgcn_mfma_f32_16x16x32_bf16(fa[i], fb[j], acc[i][j], 0, 0, 0);
        }
        __syncthreads();
    }

#pragma unroll
    for (int i = 0; i < 4; i++)
#pragma unroll
        for (int j = 0; j < 4; j++) {
            int m0  = rowbase + wm * 64 + i * 16 + quad * 4;
            int col = colbase + wn * 64 + j * 16 + l16;
            int part = col >> 10, rem = col & 1023;
            int head = rem >> 6, d = rem & 63;
            ushort* dst = (part == 0) ? qp : (part == 1) ? kp : vp;
#pragma unroll
            for (int r = 0; r < 4; r++) {
                float v = acc[i][j][r];
                int mm = m0 + r;
                int b = mm >> 11, nn = mm & 2047;
                float sv = (part == 0) ? v * 0.125f : v;   // fold 1/sqrt(64) into q
                dst[((((long)b * HEADS + head) * SEQ + nn) << 6) + d] = f2b(sv);
            }
        }
}

// ------- Proj GEMM: 128x64 tile, BK=64; grid 512 = 2 blocks/CU ---------------
// A in q-layout [B,H,N,D] (attention output); C + fp32 bias + fp32 residual.
// 4 waves: wave w owns rows w*32..w*32+31 (2 row-subtiles), all 64 cols.
__global__ __launch_bounds__(256, 3)
void gemm_proj_k(const ushort* __restrict__ A, const ushort* __restrict__ Bt,
                 const float* __restrict__ bias, const float* __restrict__ xres,
                 float* __restrict__ outp) {
    __shared__ ushort As[2][128][32];   // 16 KB
    __shared__ ushort Bs[2][64][32];    // 8 KB
    int tid  = threadIdx.x;
    int wid  = tid >> 6, lane = tid & 63;
    int quad = lane >> 4, l16 = lane & 15;
    int rowbase = blockIdx.y * 128;
    int colbase = blockIdx.x * 64;
    int arow = lane >> 2, acol = (lane & 3) * 8;

    f32x4 acc[2][4];
#pragma unroll
    for (int i = 0; i < 2; i++)
#pragma unroll
        for (int j = 0; j < 4; j++) acc[i][j] = (f32x4){0.f, 0.f, 0.f, 0.f};

    for (int k0 = 0; k0 < DIM; k0 += 64) {
        // A: q-layout gather, 2 panels x 8 chunks (chunk c = wid*2+p)
#pragma unroll
        for (int p = 0; p < 2; p++) {
            int c = wid * 2 + p;
            int r = c * 16 + arow;
            int mm = rowbase + r;
            int bq = mm >> 11, nn = mm & 2047;
#pragma unroll
            for (int pnl = 0; pnl < 2; pnl++) {
                int cc = k0 + pnl * 32 + acol;
                int head = cc >> 6, d = cc & 63;
                gload_lds16(A + ((((long)bq * HEADS + head) * SEQ + nn) << 6) + d,
                            &As[pnl][c * 16][0]);
            }
        }
        // B: 64 rows, 2 panels x 4 chunks (chunk = wid)
        {
            int r = wid * 16 + arow;
#pragma unroll
            for (int pnl = 0; pnl < 2; pnl++) {
                int cc = k0 + pnl * 32 + acol;
                gload_lds16(Bt + (long)(colbase + r) * DIM + cc, &Bs[pnl][wid * 16][0]);
            }
        }
        __syncthreads();
#pragma unroll
        for (int pnl = 0; pnl < 2; pnl++) {
            bf16x8 fa[2], fb[4];
#pragma unroll
            for (int t = 0; t < 2; t++)
                fa[t] = *(const bf16x8*)(&As[pnl][wid * 32 + t * 16 + l16][quad * 8]);
#pragma unroll
            for (int t = 0; t < 4; t++)
                fb[t] = *(const bf16x8*)(&Bs[pnl][t * 16 + l16][quad * 8]);
#pragma unroll
            for (int i = 0; i < 2; i++)
#pragma unroll
                for (int j = 0; j < 4; j++)
                    acc[i][j] = __builtin_amdgcn_mfma_f32_16x16x32_bf16(fa[i], fb[j], acc[i][j], 0, 0, 0);
        }
        __syncthreads();
    }

#pragma unroll
    for (int i = 0; i < 2; i++)
#pragma unroll
        for (int j = 0; j < 4; j++) {
            int m0  = rowbase + wid * 32 + i * 16 + quad * 4;
            int col = colbase + j * 16 + l16;
#pragma unroll
            for (int r = 0; r < 4; r++) {
                int mm = m0 + r;
                outp[(long)mm * DIM + col] = acc[i][j][r] + bias[col] + xres[(long)mm * DIM + col];
            }
        }
}

// ------- flash attention, fixed-max softmax, LDS-staged K/V ------------------
// Block = 128 q-rows of one (b,h); each wave owns TWO 16-row q-subtiles.
// QK^T with SWAPPED operands -> C[key][q]; P C->A transform via 2 ds_write_b64
// per subtile; l-reduction hoisted out of the loop. In-place output into q.
__global__ __launch_bounds__(256, 2)
void attn_k(ushort* qio, const ushort* __restrict__ k,
            const ushort* __restrict__ vt) {
    __shared__ ushort Kp[2][2][1312];      // [buf][panel][32*40 + 32 pad]
    __shared__ ushort Vs[2][64][40];       // [buf][d][key]
    __shared__ ushort plds[4][2][16][40];  // [wave][subtile][q][key]
    int bh = blockIdx.y;
    int tid = threadIdx.x, wid = tid >> 6, lane = tid & 63;
    int quad = lane >> 4, l16 = lane & 15;
    ushort* qh = qio + (long)bh * SEQ * HDIM;
    const ushort* kh = k  + (long)bh * SEQ * HDIM;
    const ushort* vh = vt + (long)bh * HDIM * SEQ;

    int krow = tid >> 3, kc8 = (tid & 7) * 8;
    int kpan = kc8 >> 5, kcp = kc8 & 31;
    int koff = krow * 40 + kcp;
    int vrow = tid >> 2, vcol = (tid & 3) * 8;

    int qrow0 = blockIdx.x * 128 + wid * 32;
    bf16x8 qf[2][2];
#pragma unroll
    for (int s = 0; s < 2; s++) {
        qf[s][0] = *(const bf16x8*)(qh + (long)(qrow0 + s * 16 + l16) * HDIM + quad * 8);
        qf[s][1] = *(const bf16x8*)(qh + (long)(qrow0 + s * 16 + l16) * HDIM + 32 + quad * 8);
    }

    f32x4 o[2][4];
    f32x4 lac[2][2];
#pragma unroll
    for (int s = 0; s < 2; s++) {
#pragma unroll
        for (int dc = 0; dc < 4; dc++) o[s][dc] = (f32x4){0.f, 0.f, 0.f, 0.f};
        lac[s][0] = (f32x4){0.f, 0.f, 0.f, 0.f};
        lac[s][1] = (f32x4){0.f, 0.f, 0.f, 0.f};
    }

    uint4 kreg = *(const uint4*)(kh + (long)krow * HDIM + kc8);
    uint4 vreg = *(const uint4*)(vh + (long)vrow * SEQ + vcol);
    *(uint4*)(&Kp[0][kpan][koff]) = kreg;
    *(uint4*)(&Vs[0][vrow][vcol]) = vreg;

    const int NIT = SEQ / 32;   // 64
    for (int it = 0; it < NIT; ++it) {
        int buf = it & 1;
        if (it + 1 < NIT) {
            int kt = (it + 1) * 32;
            kreg = *(const uint4*)(kh + (long)(kt + krow) * HDIM + kc8);
            vreg = *(const uint4*)(vh + (long)vrow * SEQ + kt + vcol);
        }
        __syncthreads();

        bf16x8 kb[2][2];
#pragma unroll
        for (int t = 0; t < 2; t++)
#pragma unroll
            for (int p = 0; p < 2; p++)
                kb[t][p] = *(const bf16x8*)(&Kp[buf][p][(t * 16 + l16) * 40 + quad * 8]);

        // QK^T SWAPPED: C[key][q] — col=l16=q, row=quad*4+r=key(+t*16)
        f32x4 sc[2][2];
#pragma unroll
        for (int s = 0; s < 2; s++)
#pragma unroll
            for (int t = 0; t < 2; t++) {
                f32x4 z = (f32x4){0.f, 0.f, 0.f, 0.f};
                z = __builtin_amdgcn_mfma_f32_16x16x32_bf16(kb[t][0], qf[s][0], z, 0, 0, 0);
                z = __builtin_amdgcn_mfma_f32_16x16x32_bf16(kb[t][1], qf[s][1], z, 0, 0, 0);
                sc[s][t] = z;
            }

#pragma unroll
        for (int s = 0; s < 2; s++)
#pragma unroll
            for (int t = 0; t < 2; t++) {
                float e0 = __expf(sc[s][t][0]);
                float e1 = __expf(sc[s][t][1]);
                float e2 = __expf(sc[s][t][2]);
                float e3 = __expf(sc[s][t][3]);
                lac[s][t] += (f32x4){e0, e1, e2, e3};
                uint2 pk;
                pk.x = pack2bf(e0, e1);
                pk.y = pack2bf(e2, e3);
                *(uint2*)(&plds[wid][s][l16][t * 16 + quad * 4]) = pk;
            }
        asm volatile("s_waitcnt lgkmcnt(0)" ::: "memory");

        bf16x8 pf[2];
#pragma unroll
        for (int s = 0; s < 2; s++)
            pf[s] = *(const bf16x8*)(&plds[wid][s][l16][quad * 8]);
#pragma unroll
        for (int dc = 0; dc < 4; dc++) {
            bf16x8 vfb = *(const bf16x8*)(&Vs[buf][dc * 16 + l16][quad * 8]);
#pragma unroll
            for (int s = 0; s < 2; s++)
                o[s][dc] = __builtin_amdgcn_mfma_f32_16x16x32_bf16(pf[s], vfb, o[s][dc], 0, 0, 0);
        }

        if (it + 1 < NIT) {
            *(uint4*)(&Kp[buf ^ 1][kpan][koff]) = kreg;
            *(uint4*)(&Vs[buf ^ 1][vrow][vcol]) = vreg;
        }
    }

#pragma unroll
    for (int s = 0; s < 2; s++) {
        f32x4 lv = lac[s][0] + lac[s][1];
        float t = lv[0] + lv[1] + lv[2] + lv[3];
        t += __shfl_xor(t, 16);
        t += __shfl_xor(t, 32);
        float linv_q = 1.0f / t;   // valid for q = l16 in every lane
        float linv[4];
#pragma unroll
        for (int r = 0; r < 4; r++)
            linv[r] = __shfl(linv_q, quad * 4 + r);
        int rowo = qrow0 + s * 16 + quad * 4;
#pragma unroll
        for (int dc = 0; dc < 4; dc++)
#pragma unroll
            for (int r = 0; r < 4; r++)
                qh[(long)(rowo + r) * HDIM + dc * 16 + l16] = f2b(o[s][dc][r] * linv[r]);
    }
}

// ------- launch --------------------------------------------------------------
extern "C" void kernel_launch(void* const* d_in, const int* in_sizes, int n_in,
                              void* d_out, int out_size, void* d_ws, size_t ws_size,
                              hipStream_t stream) {
    const float* x      = (const float*)d_in[0];
    const float* w_qkv  = (const float*)d_in[1];
    const float* w_proj = (const float*)d_in[2];
    const float* b_proj = (const float*)d_in[3];
    const float* gamma  = (const float*)d_in[4];
    const float* beta   = (const float*)d_in[5];
    float* out = (float*)d_out;

    // workspace: 19M bf16 elements = 38 MB (slots reused across phases)
    ushort* ws   = (ushort*)d_ws;
    ushort* h_vt = ws;                      // 4M: h (phase 2-3), then V^T (phase 4-5)
    ushort* wqt  = ws + (size_t)4 * MEG;    // 3M: w_qkv^T (bf16)
    ushort* qb   = ws + (size_t)7 * MEG;    // 4M: q (pre-scaled), then attn out (q-layout)
    ushort* kb   = ws + (size_t)11 * MEG;   // 4M: k, then w_proj^T (phase 6-7)
    ushort* vb   = ws + (size_t)15 * MEG;   // 4M: v

    // 1) transpose+cast w_qkv f32[K][3N] -> bf16 [3N][K]
    transpose_f2b_k<<<dim3(3 * DIM / 32, DIM / 32), dim3(32, 8), 0, stream>>>(
        w_qkv, wqt, DIM, 3 * DIM);
    // 2) layernorm f32 -> bf16 h
    ln_k<<<dim3(TOK), dim3(256), 0, stream>>>(x, gamma, beta, h_vt);
    // 3) qkv gemm + scatter to q/k/v (bf16; q pre-scaled by 0.125)
    gemm_qkv_k<<<dim3(3 * DIM / 128, TOK / 128), dim3(256), 0, stream>>>(
        h_vt, wqt, qb, kb, vb);
    // 4) per-head V transpose -> [D][N] (into dead h slot)
    transpose_bf16_k<<<dim3(HDIM / 32, SEQ / 32, BATCH * HEADS), dim3(32, 8), 0, stream>>>(
        vb, h_vt, SEQ, HDIM, (long)SEQ * HDIM, (long)SEQ * HDIM);
    // 5) flash attention; output overwrites q buffer in q-layout
    attn_k<<<dim3(SEQ / 128, BATCH * HEADS), dim3(256), 0, stream>>>(qb, kb, h_vt);
    // 6) transpose+cast w_proj into dead k slot
    transpose_f2b_k<<<dim3(DIM / 32, DIM / 32), dim3(32, 8), 0, stream>>>(
        w_proj, kb, DIM, DIM);
    // 7) proj gemm (+fp32 bias +fp32 residual) -> fp32 out, 128x64 tiles
    gemm_proj_k<<<dim3(DIM / 64, TOK / 128), dim3(256), 0, stream>>>(
        qb, kb, b_proj, x, out);
}

// Round 10
// 191.562 us; speedup vs baseline: 1.1782x; 1.0492x over previous
//
#include <hip/hip_runtime.h>

#define DIM   1024
#define HEADS 16
#define HDIM  64
#define BATCH 2
#define SEQ   2048
#define TOK   (BATCH*SEQ)   // 4096
#define MEG   1048576

typedef __bf16 bf16x8 __attribute__((ext_vector_type(8)));
typedef float  f32x4  __attribute__((ext_vector_type(4)));

__device__ __forceinline__ float b2f(ushort u) {
    union { unsigned int u32; float f; } x; x.u32 = ((unsigned int)u) << 16; return x.f;
}
__device__ __forceinline__ ushort f2b(float f) {
    union { float f; unsigned int u32; } x; x.f = f;
    unsigned int r = x.u32 + 0x7FFFu + ((x.u32 >> 16) & 1u);
    return (ushort)(r >> 16);
}
__device__ __forceinline__ unsigned int pack2bf(float a, float b) {  // trunc, b in hi
    union { float f; unsigned int u; } xa, xb; xa.f = a; xb.f = b;
    return (xb.u & 0xFFFF0000u) | (xa.u >> 16);
}
// async global->LDS, 16B per lane; lds dest = wave-uniform base + lane*16
__device__ __forceinline__ void gload_lds16(const ushort* g, void* l) {
    __builtin_amdgcn_global_load_lds((const __attribute__((address_space(1))) void*)g,
                                     (__attribute__((address_space(3))) void*)l, 16, 0, 0);
}

// ------- tiled transpose + fp32->bf16 cast: src f32[R][Cc] -> dst bf16[Cc][R]
__global__ void transpose_f2b_k(const float* __restrict__ src, ushort* __restrict__ dst,
                                int R, int Cc) {
    __shared__ ushort tile[32][33];
    int c0 = blockIdx.x * 32, r0 = blockIdx.y * 32;
    int tx = threadIdx.x, ty = threadIdx.y;   // 32 x 8
#pragma unroll
    for (int i = 0; i < 4; i++)
        tile[ty + 8 * i][tx] = f2b(src[(long)(r0 + ty + 8 * i) * Cc + c0 + tx]);
    __syncthreads();
#pragma unroll
    for (int i = 0; i < 4; i++)
        dst[(long)(c0 + ty + 8 * i) * R + r0 + tx] = tile[tx][ty + 8 * i];
}

// ------- LayerNorm: one block per token, fp32 in -> bf16 out -----------------
__global__ __launch_bounds__(256)
void ln_k(const float* __restrict__ x, const float* __restrict__ gamma,
          const float* __restrict__ beta, ushort* __restrict__ h) {
    __shared__ float red[8];
    int row = blockIdx.x, tid = threadIdx.x;
    const float* xr = x + (long)row * DIM;
    float4 xv = *(const float4*)(xr + tid * 4);
    float s1 = xv.x + xv.y + xv.z + xv.w;
    float s2 = xv.x * xv.x + xv.y * xv.y + xv.z * xv.z + xv.w * xv.w;
#pragma unroll
    for (int off = 32; off; off >>= 1) {
        s1 += __shfl_down(s1, off);
        s2 += __shfl_down(s2, off);
    }
    int wid = tid >> 6, lane = tid & 63;
    if (lane == 0) { red[wid * 2] = s1; red[wid * 2 + 1] = s2; }
    __syncthreads();
    s1 = red[0] + red[2] + red[4] + red[6];
    s2 = red[1] + red[3] + red[5] + red[7];
    float mu  = s1 * (1.0f / DIM);
    float var = s2 * (1.0f / DIM) - mu * mu;
    float rs  = rsqrtf(var + 1e-5f);
    float4 gv = *(const float4*)(gamma + tid * 4);
    float4 bv = *(const float4*)(beta + tid * 4);
    ushort4 ov;
    ov.x = f2b((xv.x - mu) * rs * gv.x + bv.x);
    ov.y = f2b((xv.y - mu) * rs * gv.y + bv.y);
    ov.z = f2b((xv.z - mu) * rs * gv.z + bv.z);
    ov.w = f2b((xv.w - mu) * rs * gv.w + bv.w);
    *(ushort4*)(h + (long)row * DIM + tid * 4) = ov;
}

// ------- QKV GEMM: 128x128 tile, BK=64, global_load_lds staging --------------
// Col-tiles < 2048: scatter q/k to [B,H,N,D] (q pre-scaled 1/8).
// Col-tiles >= 2048 (pure V): LDS-transpose acc and write V^T [B,H][D][N]
// coalesced — raw v never materializes, no separate transpose kernel.
__global__ __launch_bounds__(256, 3)
void gemm_qkv_k(const ushort* __restrict__ A, const ushort* __restrict__ Bt,
                ushort* __restrict__ qp, ushort* __restrict__ kp, ushort* __restrict__ vp) {
    __shared__ ushort smem[16384];   // As: [0,8192) Bs: [8192,16384); reused as T[128][128]
    int tid  = threadIdx.x;
    int wid  = tid >> 6, lane = tid & 63;
    int quad = lane >> 4, l16 = lane & 15;
    int wm = wid >> 1, wn = wid & 1;
    int rowbase = blockIdx.y * 128;
    int colbase = blockIdx.x * 128;

    f32x4 acc[4][4];
#pragma unroll
    for (int i = 0; i < 4; i++)
#pragma unroll
        for (int j = 0; j < 4; j++) acc[i][j] = (f32x4){0.f, 0.f, 0.f, 0.f};

    for (int k0 = 0; k0 < DIM; k0 += 64) {
#pragma unroll
        for (int p = 0; p < 2; p++) {
            int c = wid * 2 + p;
            int r = c * 16 + (lane >> 2);
            int ac = (lane & 3) * 8;
#pragma unroll
            for (int pnl = 0; pnl < 2; pnl++) {
                int cc = k0 + pnl * 32 + ac;
                gload_lds16(A  + (long)(rowbase + r) * DIM + cc,
                            &smem[pnl * 4096 + c * 16 * 32]);
                gload_lds16(Bt + (long)(colbase + r) * DIM + cc,
                            &smem[8192 + pnl * 4096 + c * 16 * 32]);
            }
        }
        __syncthreads();
#pragma unroll
        for (int pnl = 0; pnl < 2; pnl++) {
            bf16x8 fa[4], fb[4];
#pragma unroll
            for (int t = 0; t < 4; t++)
                fa[t] = *(const bf16x8*)(&smem[pnl * 4096 + (wm * 64 + t * 16 + l16) * 32 + quad * 8]);
#pragma unroll
            for (int t = 0; t < 4; t++)
                fb[t] = *(const bf16x8*)(&smem[8192 + pnl * 4096 + (wn * 64 + t * 16 + l16) * 32 + quad * 8]);
#pragma unroll
            for (int i = 0; i < 4; i++)
#pragma unroll
                for (int j = 0; j < 4; j++)
                    acc[i][j] = __builtin_amdgcn_mfma_f32_16x16x32_bf16(fa[i], fb[j], acc[i][j], 0, 0, 0);
        }
        __syncthreads();
    }

    if (colbase >= 2048) {
        // V block: acc -> T[col_local][row_local] -> coalesced V^T write
#pragma unroll
        for (int i = 0; i < 4; i++)
#pragma unroll
            for (int j = 0; j < 4; j++) {
                int cl = wn * 64 + j * 16 + l16;
                int rl = wm * 64 + i * 16 + quad * 4;
#pragma unroll
                for (int r = 0; r < 4; r++)
                    smem[cl * 128 + rl + r] = f2b(acc[i][j][r]);
            }
        __syncthreads();
        int b = rowbase >> 11, nnb = rowbase & 2047;
        int hbase = (colbase - 2048) >> 6;
#pragma unroll
        for (int i = 0; i < 8; i++) {
            int id = i * 256 + tid;           // 0..2047
            int cl = id >> 4;                 // local col 0..127
            int off = (id & 15) * 8;          // 0..120
            int hh = hbase + (cl >> 6), d = cl & 63;
            uint4 val = *(const uint4*)(&smem[cl * 128 + off]);
            *(uint4*)(vp + (((long)b * HEADS + hh) * HDIM + d) * SEQ + nnb + off) = val;
        }
    } else {
#pragma unroll
        for (int i = 0; i < 4; i++)
#pragma unroll
            for (int j = 0; j < 4; j++) {
                int m0  = rowbase + wm * 64 + i * 16 + quad * 4;
                int col = colbase + wn * 64 + j * 16 + l16;
                int part = col >> 10, rem = col & 1023;
                int head = rem >> 6, d = rem & 63;
                ushort* dst = (part == 0) ? qp : kp;
#pragma unroll
                for (int r = 0; r < 4; r++) {
                    float v = acc[i][j][r];
                    int mm = m0 + r;
                    int b = mm >> 11, nn = mm & 2047;
                    float sv = (part == 0) ? v * 0.125f : v;   // fold 1/sqrt(64) into q
                    dst[((((long)b * HEADS + head) * SEQ + nn) << 6) + d] = f2b(sv);
                }
            }
    }
}

// ------- Proj GEMM: 128x64 tile, BK=64; grid 512 -----------------------------
__global__ __launch_bounds__(256, 3)
void gemm_proj_k(const ushort* __restrict__ A, const ushort* __restrict__ Bt,
                 const float* __restrict__ bias, const float* __restrict__ xres,
                 float* __restrict__ outp) {
    __shared__ ushort As[2][128][32];   // 16 KB
    __shared__ ushort Bs[2][64][32];    // 8 KB
    int tid  = threadIdx.x;
    int wid  = tid >> 6, lane = tid & 63;
    int quad = lane >> 4, l16 = lane & 15;
    int rowbase = blockIdx.y * 128;
    int colbase = blockIdx.x * 64;
    int arow = lane >> 2, acol = (lane & 3) * 8;

    f32x4 acc[2][4];
#pragma unroll
    for (int i = 0; i < 2; i++)
#pragma unroll
        for (int j = 0; j < 4; j++) acc[i][j] = (f32x4){0.f, 0.f, 0.f, 0.f};

    for (int k0 = 0; k0 < DIM; k0 += 64) {
#pragma unroll
        for (int p = 0; p < 2; p++) {
            int c = wid * 2 + p;
            int r = c * 16 + arow;
            int mm = rowbase + r;
            int bq = mm >> 11, nn = mm & 2047;
#pragma unroll
            for (int pnl = 0; pnl < 2; pnl++) {
                int cc = k0 + pnl * 32 + acol;
                int head = cc >> 6, d = cc & 63;
                gload_lds16(A + ((((long)bq * HEADS + head) * SEQ + nn) << 6) + d,
                            &As[pnl][c * 16][0]);
            }
        }
        {
            int r = wid * 16 + arow;
#pragma unroll
            for (int pnl = 0; pnl < 2; pnl++) {
                int cc = k0 + pnl * 32 + acol;
                gload_lds16(Bt + (long)(colbase + r) * DIM + cc, &Bs[pnl][wid * 16][0]);
            }
        }
        __syncthreads();
#pragma unroll
        for (int pnl = 0; pnl < 2; pnl++) {
            bf16x8 fa[2], fb[4];
#pragma unroll
            for (int t = 0; t < 2; t++)
                fa[t] = *(const bf16x8*)(&As[pnl][wid * 32 + t * 16 + l16][quad * 8]);
#pragma unroll
            for (int t = 0; t < 4; t++)
                fb[t] = *(const bf16x8*)(&Bs[pnl][t * 16 + l16][quad * 8]);
#pragma unroll
            for (int i = 0; i < 2; i++)
#pragma unroll
                for (int j = 0; j < 4; j++)
                    acc[i][j] = __builtin_amdgcn_mfma_f32_16x16x32_bf16(fa[i], fb[j], acc[i][j], 0, 0, 0);
        }
        __syncthreads();
    }

#pragma unroll
    for (int i = 0; i < 2; i++)
#pragma unroll
        for (int j = 0; j < 4; j++) {
            int m0  = rowbase + wid * 32 + i * 16 + quad * 4;
            int col = colbase + j * 16 + l16;
#pragma unroll
            for (int r = 0; r < 4; r++) {
                int mm = m0 + r;
                outp[(long)mm * DIM + col] = acc[i][j][r] + bias[col] + xres[(long)mm * DIM + col];
            }
        }
}

// ------- flash attention, fixed-max softmax, conflict-free LDS (stride 72) ---
// Row stride 72 ushorts = 36 banks (36/4=9 odd): frag-read group
// (9*l16+quad) mod 8 is uniform -> b128 reads at the 8-cycle floor.
// Staging row-major (row=tid&31/63) -> write groups uniform too.
__global__ __launch_bounds__(256, 2)
void attn_k(ushort* qio, const ushort* __restrict__ k,
            const ushort* __restrict__ vt) {
    __shared__ ushort Kp[2][2][2304];    // [buf][panel][32*72]
    __shared__ ushort Vs[2][4608];       // [buf][64*72]
    __shared__ ushort plds[4][2][1152];  // [wave][sub][16*72]
    int bh = blockIdx.y;
    int tid = threadIdx.x, wid = tid >> 6, lane = tid & 63;
    int quad = lane >> 4, l16 = lane & 15;
    ushort* qh = qio + (long)bh * SEQ * HDIM;
    const ushort* kh = k  + (long)bh * SEQ * HDIM;
    const ushort* vh = vt + (long)bh * HDIM * SEQ;

    // staging: K tile 32x64 (row=tid&31, col8=(tid>>5)*8); V^T 64x32
    int krow = tid & 31, kc8 = (tid >> 5) * 8;
    int kpan = kc8 >> 5, kcp = kc8 & 31;
    int koff = krow * 72 + kcp;
    int vrow = tid & 63, vcol = (tid >> 6) * 8;
    int voff = vrow * 72 + vcol;

    int qrow0 = blockIdx.x * 128 + wid * 32;
    bf16x8 qf[2][2];
#pragma unroll
    for (int s = 0; s < 2; s++) {
        qf[s][0] = *(const bf16x8*)(qh + (long)(qrow0 + s * 16 + l16) * HDIM + quad * 8);
        qf[s][1] = *(const bf16x8*)(qh + (long)(qrow0 + s * 16 + l16) * HDIM + 32 + quad * 8);
    }

    f32x4 o[2][4];
    f32x4 lac[2][2];
#pragma unroll
    for (int s = 0; s < 2; s++) {
#pragma unroll
        for (int dc = 0; dc < 4; dc++) o[s][dc] = (f32x4){0.f, 0.f, 0.f, 0.f};
        lac[s][0] = (f32x4){0.f, 0.f, 0.f, 0.f};
        lac[s][1] = (f32x4){0.f, 0.f, 0.f, 0.f};
    }

    uint4 kreg = *(const uint4*)(kh + (long)krow * HDIM + kc8);
    uint4 vreg = *(const uint4*)(vh + (long)vrow * SEQ + vcol);
    *(uint4*)(&Kp[0][kpan][koff]) = kreg;
    *(uint4*)(&Vs[0][voff]) = vreg;

    const int NIT = SEQ / 32;   // 64
    for (int it = 0; it < NIT; ++it) {
        int buf = it & 1;
        if (it + 1 < NIT) {
            int kt = (it + 1) * 32;
            kreg = *(const uint4*)(kh + (long)(kt + krow) * HDIM + kc8);
            vreg = *(const uint4*)(vh + (long)vrow * SEQ + kt + vcol);
        }
        __syncthreads();

        bf16x8 kb[2][2];
#pragma unroll
        for (int t = 0; t < 2; t++)
#pragma unroll
            for (int p = 0; p < 2; p++)
                kb[t][p] = *(const bf16x8*)(&Kp[buf][p][(t * 16 + l16) * 72 + quad * 8]);

        // QK^T SWAPPED: C[key][q] — col=l16=q, row=quad*4+r=key(+t*16)
        f32x4 sc[2][2];
#pragma unroll
        for (int s = 0; s < 2; s++)
#pragma unroll
            for (int t = 0; t < 2; t++) {
                f32x4 z = (f32x4){0.f, 0.f, 0.f, 0.f};
                z = __builtin_amdgcn_mfma_f32_16x16x32_bf16(kb[t][0], qf[s][0], z, 0, 0, 0);
                z = __builtin_amdgcn_mfma_f32_16x16x32_bf16(kb[t][1], qf[s][1], z, 0, 0, 0);
                sc[s][t] = z;
            }

#pragma unroll
        for (int s = 0; s < 2; s++)
#pragma unroll
            for (int t = 0; t < 2; t++) {
                float e0 = __expf(sc[s][t][0]);
                float e1 = __expf(sc[s][t][1]);
                float e2 = __expf(sc[s][t][2]);
                float e3 = __expf(sc[s][t][3]);
                lac[s][t] += (f32x4){e0, e1, e2, e3};
                uint2 pk;
                pk.x = pack2bf(e0, e1);
                pk.y = pack2bf(e2, e3);
                *(uint2*)(&plds[wid][s][l16 * 72 + t * 16 + quad * 4]) = pk;
            }
        asm volatile("s_waitcnt lgkmcnt(0)" ::: "memory");

        bf16x8 pf[2];
#pragma unroll
        for (int s = 0; s < 2; s++)
            pf[s] = *(const bf16x8*)(&plds[wid][s][l16 * 72 + quad * 8]);
#pragma unroll
        for (int dc = 0; dc < 4; dc++) {
            bf16x8 vfb = *(const bf16x8*)(&Vs[buf][(dc * 16 + l16) * 72 + quad * 8]);
#pragma unroll
            for (int s = 0; s < 2; s++)
                o[s][dc] = __builtin_amdgcn_mfma_f32_16x16x32_bf16(pf[s], vfb, o[s][dc], 0, 0, 0);
        }

        if (it + 1 < NIT) {
            *(uint4*)(&Kp[buf ^ 1][kpan][koff]) = kreg;
            *(uint4*)(&Vs[buf ^ 1][voff]) = vreg;
        }
    }

#pragma unroll
    for (int s = 0; s < 2; s++) {
        f32x4 lv = lac[s][0] + lac[s][1];
        float t = lv[0] + lv[1] + lv[2] + lv[3];
        t += __shfl_xor(t, 16);
        t += __shfl_xor(t, 32);
        float linv_q = 1.0f / t;   // valid for q = l16 in every lane
        float linv[4];
#pragma unroll
        for (int r = 0; r < 4; r++)
            linv[r] = __shfl(linv_q, quad * 4 + r);
        int rowo = qrow0 + s * 16 + quad * 4;
#pragma unroll
        for (int dc = 0; dc < 4; dc++)
#pragma unroll
            for (int r = 0; r < 4; r++)
                qh[(long)(rowo + r) * HDIM + dc * 16 + l16] = f2b(o[s][dc][r] * linv[r]);
    }
}

// ------- launch --------------------------------------------------------------
extern "C" void kernel_launch(void* const* d_in, const int* in_sizes, int n_in,
                              void* d_out, int out_size, void* d_ws, size_t ws_size,
                              hipStream_t stream) {
    const float* x      = (const float*)d_in[0];
    const float* w_qkv  = (const float*)d_in[1];
    const float* w_proj = (const float*)d_in[2];
    const float* b_proj = (const float*)d_in[3];
    const float* gamma  = (const float*)d_in[4];
    const float* beta   = (const float*)d_in[5];
    float* out = (float*)d_out;

    // workspace: 19M bf16 elements = 38 MB
    ushort* ws   = (ushort*)d_ws;
    ushort* h    = ws;                      // 4M: LN output
    ushort* wqt  = ws + (size_t)4 * MEG;    // 3M: w_qkv^T (bf16)
    ushort* qb   = ws + (size_t)7 * MEG;    // 4M: q (pre-scaled), then attn out (q-layout)
    ushort* kb   = ws + (size_t)11 * MEG;   // 4M: k, then w_proj^T
    ushort* vtb  = ws + (size_t)15 * MEG;   // 4M: V^T [B,H][D][N] (written by QKV epilogue)

    // 1) transpose+cast w_qkv f32[K][3N] -> bf16 [3N][K]
    transpose_f2b_k<<<dim3(3 * DIM / 32, DIM / 32), dim3(32, 8), 0, stream>>>(
        w_qkv, wqt, DIM, 3 * DIM);
    // 2) layernorm f32 -> bf16 h
    ln_k<<<dim3(TOK), dim3(256), 0, stream>>>(x, gamma, beta, h);
    // 3) qkv gemm: scatter q/k, V^T written directly (fused transpose)
    gemm_qkv_k<<<dim3(3 * DIM / 128, TOK / 128), dim3(256), 0, stream>>>(
        h, wqt, qb, kb, vtb);
    // 4) flash attention; output overwrites q buffer in q-layout
    attn_k<<<dim3(SEQ / 128, BATCH * HEADS), dim3(256), 0, stream>>>(qb, kb, vtb);
    // 5) transpose+cast w_proj into dead k slot
    transpose_f2b_k<<<dim3(DIM / 32, DIM / 32), dim3(32, 8), 0, stream>>>(
        w_proj, kb, DIM, DIM);
    // 6) proj gemm (+fp32 bias +fp32 residual) -> fp32 out, 128x64 tiles
    gemm_proj_k<<<dim3(DIM / 64, TOK / 128), dim3(256), 0, stream>>>(
        qb, kb, b_proj, x, out);
}